// Round 10
// baseline (117.608 us; speedup 1.0000x reference)
//
#include <hip/hip_runtime.h>
#include <math.h>

#define Bc 4
#define Cc 64
#define Hh 96
#define Ww 96
#define Oo 128
#define HW 9216          // Hh*Ww
#define PT 32            // positions per block
#define NPB 288          // 32-pos tiles per image
#define RW 34            // staged region width
#define RS 72            // region col stride (bf16), 144 B (16B-aligned rows)

typedef __attribute__((ext_vector_type(8))) short bf16x8;
typedef __attribute__((ext_vector_type(4))) float f32x4;

__device__ inline unsigned short f2bf(float f) {
    unsigned u = __builtin_bit_cast(unsigned, f);
    return (unsigned short)((u + 0x7FFF + ((u >> 16) & 1)) >> 16);  // RNE
}
__device__ inline float bf2f(short s) {
    return __builtin_bit_cast(float, ((unsigned)(unsigned short)s) << 16);
}

// ---------------------------------------------------------------------------
// k_pre: (blocks 0..359) pack weights into MFMA fragment layouts;
//        (blocks 360..503) transpose x -> channels-last bf16 xT[b][h][w][c].
//  wTmF: A-frags of main W. fb = k*16 + m*2 + s ; elem[l][j] =
//        W[oc = m*16 + (l&15)][c = s*32 + (l>>4)*8 + j]
//  w27F: B-frags of offset/mod W. fb2 = (k*2+s)*2 + nt
// ---------------------------------------------------------------------------
__global__ __launch_bounds__(256) void k_pre(
    const float* __restrict__ dw, const float* __restrict__ ow,
    const float* __restrict__ mw, const float* __restrict__ x,
    unsigned short* __restrict__ wTmF, unsigned short* __restrict__ w27F,
    unsigned short* __restrict__ xT)
{
    const int bid = blockIdx.x;
    const int t = threadIdx.x;
    if (bid < 360) {
        int i = bid * 256 + t;
        if (i < 9 * 8 * 2 * 512) {
            int j = i & 7, l = (i >> 3) & 63, fb = i >> 9;
            int s = fb & 1, m = (fb >> 1) & 7, k = fb >> 4;
            int oc = m * 16 + (l & 15);
            int c = s * 32 + (l >> 4) * 8 + j;
            wTmF[i] = f2bf(dw[(oc * 64 + c) * 9 + k]);
        }
        int jj = i - 9 * 8 * 2 * 512;
        if (jj >= 0 && jj < 9 * 2 * 2 * 512) {
            int j = jj & 7, l = (jj >> 3) & 63, fb2 = jj >> 9;
            int nt = fb2 & 1, s = (fb2 >> 1) & 1, k = fb2 >> 2;
            int ch = nt * 16 + (l & 15);
            int c = s * 32 + (l >> 4) * 8 + j;
            float v = 0.f;
            if (ch < 18)      v = ow[(ch * 64 + c) * 9 + k];
            else if (ch < 27) v = mw[((ch - 18) * 64 + c) * 9 + k];
            w27F[jj] = f2bf(v);
        }
    } else {
        int gp = (bid - 360) * 256 + t;          // 0..36863, one position each
        int b = gp / HW;
        int p = gp - b * HW;
        const float* xb = x + (size_t)b * Cc * HW + p;
        unsigned short* op = xT + (size_t)gp * 64;
#pragma unroll
        for (int q = 0; q < 8; ++q) {
            union { bf16x8 v8; unsigned short us[8]; } u;
#pragma unroll
            for (int c = 0; c < 8; ++c)
                u.us[c] = f2bf(xb[(size_t)(q * 8 + c) * HW]);
            *(bf16x8*)(op + q * 8) = u.v8;
        }
    }
}

// ---------------------------------------------------------------------------
// sample+GEMM over taps [K0,K1): each wave samples its 16 positions once per
// tap and runs MFMA over ALL 128 ocs. DISTANCE-2 gather pipeline: 3 corner
// buffer sets rotating on the compile-time half-step index (fully unrolled,
// all buffer indices constant-fold -> registers, no scratch).
// ---------------------------------------------------------------------------
template <int K0, int K1>
__device__ __forceinline__ void sample_gemm(
    const unsigned short* __restrict__ xTb,
    const unsigned short* __restrict__ wb,
    const float (&pw)[9][4][PT], const int (&pi)[9][4][PT],
    int pos_l, int cq, f32x4 (&acc)[8])
{
    constexpr int NH = 2 * (K1 - K0);        // half-steps (K granularity 32)
    bf16x8 buf[3][4];

    auto issue = [&](int hs) {               // hs is compile-time post-unroll
        const int kk = K0 + (hs >> 1), so = (hs & 1) * 32;
#pragma unroll
        for (int cr = 0; cr < 4; ++cr)
            buf[hs % 3][cr] =
                *(const bf16x8*)(xTb + pi[kk][cr][pos_l] + so + cq);
    };

    issue(0);
    issue(1);

#pragma unroll
    for (int hs = 0; hs < NH; ++hs) {
        if (hs + 2 < NH) issue(hs + 2);      // distance-2 prefetch
        const int kk = K0 + (hs >> 1), s = hs & 1;
        const float w0 = pw[kk][0][pos_l], w1 = pw[kk][1][pos_l];
        const float w2 = pw[kk][2][pos_l], w3 = pw[kk][3][pos_l];
        union { bf16x8 v8; unsigned short us[8]; } B;
#pragma unroll
        for (int j = 0; j < 8; ++j)
            B.us[j] = f2bf(w0 * bf2f(buf[hs % 3][0][j])
                         + w1 * bf2f(buf[hs % 3][1][j])
                         + w2 * bf2f(buf[hs % 3][2][j])
                         + w3 * bf2f(buf[hs % 3][3][j]));
#pragma unroll
        for (int m = 0; m < 8; ++m) {
            bf16x8 A = *(const bf16x8*)(wb + (size_t)((kk * 16 + m * 2 + s) << 9));
            acc[m] = __builtin_amdgcn_mfma_f32_16x16x32_bf16(A, B.v8, acc[m], 0, 0, 0);
        }
    }
}

// ---------------------------------------------------------------------------
// k_fused: offset/mask conv (MFMA, LDS region) -> sigmoid -> bilinear params
// -> tap-split register sampling + MFMA GEMM -> LDS merge -> store.
// Wave (nt = pos half, tg = tap group 0..4 / 5..8): each (pos,tap) sampled once.
// ---------------------------------------------------------------------------
__global__ __launch_bounds__(256, 4) void k_fused(
    const unsigned short* __restrict__ xT, const float* __restrict__ ob,
    const float* __restrict__ mb, const unsigned short* __restrict__ w27F,
    const unsigned short* __restrict__ wTmF, float* __restrict__ out)
{
    __shared__ union Ovl {
        short xreg[3 * RW * RS];                       // 14688 B, phases 0-1
        struct {
            float pw[9][4][PT];                        // 4608 B
            int   pi[9][4][PT];                        // 4608 B
        } p;                                           // phases 2-3
        float mg[8 * 520];                             // 16640 B, merge
    } ovl;
    __shared__ float offm_s[27 * 33];

    const int t = threadIdx.x;
    const int lid = (blockIdx.x & 7) * 144 + (blockIdx.x >> 3);
    const int bb = lid / NPB;
    const int tile = lid - bb * NPB;
    const int ho = tile / 3;
    const int wo0 = (tile - ho * 3) * 32;
    const int wv = t >> 6;
    const int l = t & 63;
    const int lr = l & 15;
    const int quad = l >> 4;

    const unsigned short* xTb = xT + (size_t)bb * HW * 64;

    // region stage from xT: rows ho-1..ho+1, cols wo0-1..wo0+32 (b128 copies)
    static const bf16x8 zero8 = {0, 0, 0, 0, 0, 0, 0, 0};
    for (int i = t; i < 3 * RW * 8; i += 256) {
        int q = i & 7;
        int rc = i >> 3;
        int col = rc % RW, r = rc / RW;
        int h = ho + r - 1, w = wo0 + col - 1;
        bf16x8 val = zero8;
        if ((unsigned)h < (unsigned)Hh && (unsigned)w < (unsigned)Ww)
            val = *(const bf16x8*)(xTb + ((size_t)(h * Ww + w)) * 64 + q * 8);
        *(bf16x8*)&ovl.xreg[(r * RW + col) * RS + q * 8] = val;
    }
    __syncthreads();

    // phase 1: conv 64->27 via MFMA (A from region LDS, B coalesced global)
    {
        f32x4 acc_o = {0.f, 0.f, 0.f, 0.f};
        const int mt1 = wv & 1;
        const int nt1 = wv >> 1;
#pragma unroll
        for (int k9 = 0; k9 < 9; ++k9) {
            const int di = k9 / 3, dj = k9 % 3;
            const short* ar = &ovl.xreg[(di * RW + mt1 * 16 + lr + dj) * RS + quad * 8];
#pragma unroll
            for (int s = 0; s < 2; ++s) {
                bf16x8 a = *(const bf16x8*)(ar + s * 32);
                bf16x8 b = *(const bf16x8*)(w27F + (((k9 * 2 + s) * 2 + nt1) << 9) + l * 8);
                acc_o = __builtin_amdgcn_mfma_f32_16x16x32_bf16(a, b, acc_o, 0, 0, 0);
            }
        }
        __syncthreads();                       // xreg reads complete here
        int ch = nt1 * 16 + lr;
        if (ch < 27) {
#pragma unroll
            for (int r = 0; r < 4; ++r)
                offm_s[ch * 33 + mt1 * 16 + quad * 4 + r] = acc_o[r];
        }
    }
    __syncthreads();

    // phase 2: bias + 2*sigmoid, then bilinear params (into union - xreg dead)
    for (int i = t; i < 27 * PT; i += 256) {
        int ch = i >> 5, pos = i & 31;
        float v = offm_s[ch * 33 + pos];
        if (ch < 18) v += ob[ch];
        else         v = 2.f / (1.f + expf(-(v + mb[ch - 18])));
        offm_s[ch * 33 + pos] = v;
    }
    __syncthreads();
    for (int i = t; i < 9 * PT; i += 256) {
        int kk = i >> 5, pos = i & 31;
        float dy = offm_s[(2 * kk) * 33 + pos];
        float dx = offm_s[(2 * kk + 1) * 33 + pos];
        float mm = offm_s[(18 + kk) * 33 + pos];
        float py = (float)(ho - 1 + kk / 3) + dy;
        float px = (float)(wo0 + pos - 1 + kk % 3) + dx;
        float fy = floorf(py), fx = floorf(px);
        float ly = py - fy, lx = px - fx;
        int y0 = (int)fy, x0 = (int)fx;
        int y1 = y0 + 1, x1 = x0 + 1;
        float v00 = ((unsigned)y0 < (unsigned)Hh && (unsigned)x0 < (unsigned)Ww) ? 1.f : 0.f;
        float v01 = ((unsigned)y0 < (unsigned)Hh && (unsigned)x1 < (unsigned)Ww) ? 1.f : 0.f;
        float v10 = ((unsigned)y1 < (unsigned)Hh && (unsigned)x0 < (unsigned)Ww) ? 1.f : 0.f;
        float v11 = ((unsigned)y1 < (unsigned)Hh && (unsigned)x1 < (unsigned)Ww) ? 1.f : 0.f;
        int cy0 = min(max(y0, 0), Hh - 1), cy1 = min(max(y1, 0), Hh - 1);
        int cx0 = min(max(x0, 0), Ww - 1), cx1 = min(max(x1, 0), Ww - 1);
        ovl.p.pw[kk][0][pos] = (1.f - ly) * (1.f - lx) * mm * v00;
        ovl.p.pw[kk][1][pos] = (1.f - ly) * lx * mm * v01;
        ovl.p.pw[kk][2][pos] = ly * (1.f - lx) * mm * v10;
        ovl.p.pw[kk][3][pos] = ly * lx * mm * v11;
        ovl.p.pi[kk][0][pos] = (cy0 * Ww + cx0) * 64;
        ovl.p.pi[kk][1][pos] = (cy0 * Ww + cx1) * 64;
        ovl.p.pi[kk][2][pos] = (cy1 * Ww + cx0) * 64;
        ovl.p.pi[kk][3][pos] = (cy1 * Ww + cx1) * 64;
    }
    __syncthreads();

    // phase 3: tap-split sampling + GEMM over all 128 ocs
    const int nt = wv & 1;                   // pos half
    const int tg = wv >> 1;                  // tap group
    const int pos_l = nt * 16 + lr;
    const int cq = quad * 8;

    f32x4 acc[8];
#pragma unroll
    for (int m = 0; m < 8; ++m) acc[m] = (f32x4){0.f, 0.f, 0.f, 0.f};

    const unsigned short* wb = wTmF + l * 8;

    if (tg == 0)
        sample_gemm<0, 5>(xTb, wb, ovl.p.pw, ovl.p.pi, pos_l, cq, acc);
    else
        sample_gemm<5, 9>(xTb, wb, ovl.p.pw, ovl.p.pi, pos_l, cq, acc);

    __syncthreads();                          // all pw/pi reads done
    if (tg == 1) {
#pragma unroll
        for (int m = 0; m < 8; ++m)
            *(f32x4*)&ovl.mg[m * 520 + (nt * 64 + l) * 4] = acc[m];
    }
    __syncthreads();
    if (tg == 0) {
        float* outp = out + (size_t)bb * Oo * HW + tile * PT + nt * 16 + lr;
#pragma unroll
        for (int m = 0; m < 8; ++m) {
            f32x4 o = acc[m] + *(const f32x4*)&ovl.mg[m * 520 + (nt * 64 + l) * 4];
#pragma unroll
            for (int r = 0; r < 4; ++r) {
                int oc = m * 16 + quad * 4 + r;
                outp[(size_t)oc * HW] = o[r];
            }
        }
    }
}

extern "C" void kernel_launch(void* const* d_in, const int* in_sizes, int n_in,
                              void* d_out, int out_size, void* d_ws, size_t ws_size,
                              hipStream_t stream) {
    const float* x  = (const float*)d_in[0];
    const float* ow = (const float*)d_in[1];
    const float* ob = (const float*)d_in[2];
    const float* mw = (const float*)d_in[3];
    const float* mb = (const float*)d_in[4];
    const float* dw = (const float*)d_in[5];
    float* out = (float*)d_out;

    unsigned short* wTmF = (unsigned short*)d_ws;          // 73728 shorts
    unsigned short* w27F = wTmF + 9 * 8 * 2 * 512;         // 18432 shorts
    unsigned short* xT   = w27F + 9 * 2 * 2 * 512;         // 2359296 shorts

    hipLaunchKernelGGL(k_pre, dim3(504), dim3(256), 0, stream,
                       dw, ow, mw, x, wTmF, w27F, xT);
    hipLaunchKernelGGL(k_fused, dim3(Bc * NPB), dim3(256), 0, stream,
                       xT, ob, mb, w27F, wTmF, out);
}

// Round 11
// 106.684 us; speedup vs baseline: 1.1024x; 1.1024x over previous
//
#include <hip/hip_runtime.h>
#include <math.h>

#define Bc 4
#define Cc 64
#define Hh 96
#define Ww 96
#define Oo 128
#define HW 9216          // Hh*Ww
#define PT 32            // positions per block
#define NPB 288          // 32-pos tiles per image
#define RR 7             // region rows  (ho-3 .. ho+3)
#define RC 38            // region cols  (wo0-3 .. wo0+34)
#define RS 72            // shorts per position record (144 B: 16B-aligned, 36 banks)

typedef __attribute__((ext_vector_type(8))) short bf16x8;
typedef __attribute__((ext_vector_type(4))) float f32x4;

__device__ inline unsigned short f2bf(float f) {
    unsigned u = __builtin_bit_cast(unsigned, f);
    return (unsigned short)((u + 0x7FFF + ((u >> 16) & 1)) >> 16);  // RNE
}
__device__ inline float bf2f(short s) {
    return __builtin_bit_cast(float, ((unsigned)(unsigned short)s) << 16);
}

// ---------------------------------------------------------------------------
// k_pre: (blocks 0..359) pack weights into MFMA fragment layouts;
//        (blocks 360..503) transpose x -> channels-last bf16 xT[b][h][w][c].
// ---------------------------------------------------------------------------
__global__ __launch_bounds__(256) void k_pre(
    const float* __restrict__ dw, const float* __restrict__ ow,
    const float* __restrict__ mw, const float* __restrict__ x,
    unsigned short* __restrict__ wTmF, unsigned short* __restrict__ w27F,
    unsigned short* __restrict__ xT)
{
    const int bid = blockIdx.x;
    const int t = threadIdx.x;
    if (bid < 360) {
        int i = bid * 256 + t;
        if (i < 9 * 8 * 2 * 512) {
            int j = i & 7, l = (i >> 3) & 63, fb = i >> 9;
            int s = fb & 1, m = (fb >> 1) & 7, k = fb >> 4;
            int oc = m * 16 + (l & 15);
            int c = s * 32 + (l >> 4) * 8 + j;
            wTmF[i] = f2bf(dw[(oc * 64 + c) * 9 + k]);
        }
        int jj = i - 9 * 8 * 2 * 512;
        if (jj >= 0 && jj < 9 * 2 * 2 * 512) {
            int j = jj & 7, l = (jj >> 3) & 63, fb2 = jj >> 9;
            int nt = fb2 & 1, s = (fb2 >> 1) & 1, k = fb2 >> 2;
            int ch = nt * 16 + (l & 15);
            int c = s * 32 + (l >> 4) * 8 + j;
            float v = 0.f;
            if (ch < 18)      v = ow[(ch * 64 + c) * 9 + k];
            else if (ch < 27) v = mw[((ch - 18) * 64 + c) * 9 + k];
            w27F[jj] = f2bf(v);
        }
    } else {
        int gp = (bid - 360) * 256 + t;          // 0..36863, one position each
        int b = gp / HW;
        int p = gp - b * HW;
        const float* xb = x + (size_t)b * Cc * HW + p;
        unsigned short* op = xT + (size_t)gp * 64;
#pragma unroll
        for (int q = 0; q < 8; ++q) {
            union { bf16x8 v8; unsigned short us[8]; } u;
#pragma unroll
            for (int c = 0; c < 8; ++c)
                u.us[c] = f2bf(xb[(size_t)(q * 8 + c) * HW]);
            *(bf16x8*)(op + q * 8) = u.v8;
        }
    }
}

// ---------------------------------------------------------------------------
// sample+GEMM over taps [K0,K1): corners come from the LDS region (fast path,
// wave-uniform ballot) with exact per-lane global fallback for tagged indices.
// ---------------------------------------------------------------------------
template <int K0, int K1>
__device__ __forceinline__ void sample_gemm(
    const short (&reg)[RR * RC * RS],
    const unsigned short* __restrict__ xTb,
    const unsigned short* __restrict__ wb,
    const float (&pw)[9][4][PT], const int (&pi)[9][4][PT],
    int pos_l, int cq, f32x4 (&acc)[8])
{
#pragma unroll
    for (int kk = K0; kk < K1; ++kk) {
        const float w0 = pw[kk][0][pos_l], w1 = pw[kk][1][pos_l];
        const float w2 = pw[kk][2][pos_l], w3 = pw[kk][3][pos_l];
        const int i0 = pi[kk][0][pos_l], i1 = pi[kk][1][pos_l];
        const int i2 = pi[kk][2][pos_l], i3 = pi[kk][3][pos_l];
        const unsigned long long anybad = __ballot((i0 | i1 | i2 | i3) < 0);

#pragma unroll
        for (int s = 0; s < 2; ++s) {
            const int so = s * 32 + cq;
            bf16x8 c0, c1, c2, c3;
            if (anybad == 0) {                       // wave-uniform fast path
                c0 = *(const bf16x8*)(&reg[i0 + so]);
                c1 = *(const bf16x8*)(&reg[i1 + so]);
                c2 = *(const bf16x8*)(&reg[i2 + so]);
                c3 = *(const bf16x8*)(&reg[i3 + so]);
            } else {                                 // rare exact fallback
                c0 = (i0 < 0) ? *(const bf16x8*)(xTb + (i0 & 0x7FFFFFFF) + so)
                              : *(const bf16x8*)(&reg[i0 + so]);
                c1 = (i1 < 0) ? *(const bf16x8*)(xTb + (i1 & 0x7FFFFFFF) + so)
                              : *(const bf16x8*)(&reg[i1 + so]);
                c2 = (i2 < 0) ? *(const bf16x8*)(xTb + (i2 & 0x7FFFFFFF) + so)
                              : *(const bf16x8*)(&reg[i2 + so]);
                c3 = (i3 < 0) ? *(const bf16x8*)(xTb + (i3 & 0x7FFFFFFF) + so)
                              : *(const bf16x8*)(&reg[i3 + so]);
            }
            union { bf16x8 v8; unsigned short us[8]; } B;
#pragma unroll
            for (int j = 0; j < 8; ++j)
                B.us[j] = f2bf(w0 * bf2f(c0[j]) + w1 * bf2f(c1[j])
                             + w2 * bf2f(c2[j]) + w3 * bf2f(c3[j]));
#pragma unroll
            for (int m = 0; m < 8; ++m) {
                bf16x8 A = *(const bf16x8*)(wb + (size_t)((kk * 16 + m * 2 + s) << 9));
                acc[m] = __builtin_amdgcn_mfma_f32_16x16x32_bf16(A, B.v8, acc[m], 0, 0, 0);
            }
        }
    }
}

// ---------------------------------------------------------------------------
// k_fused: halo region (7x38, LDS) -> offset/mask conv (MFMA) -> sigmoid ->
// bilinear params (region-relative indices) -> tap-split LDS sampling + MFMA
// GEMM -> LDS merge -> store.
// ---------------------------------------------------------------------------
__global__ __launch_bounds__(256, 3) void k_fused(
    const unsigned short* __restrict__ xT, const float* __restrict__ ob,
    const float* __restrict__ mb, const unsigned short* __restrict__ w27F,
    const unsigned short* __restrict__ wTmF, float* __restrict__ out)
{
    __shared__ union RU {
        short reg[RR * RC * RS];                   // 38304 B, phases 0-3
        float mg[8 * 520];                         // 16640 B, merge epilogue
    } R;
    __shared__ float s_pw[9][4][PT];               // 4608 B
    __shared__ int   s_pi[9][4][PT];               // 4608 B
    __shared__ float offm_s[27 * 33];              // 3564 B

    const int t = threadIdx.x;
    const int lid = (blockIdx.x & 7) * 144 + (blockIdx.x >> 3);
    const int bb = lid / NPB;
    const int tile = lid - bb * NPB;
    const int ho = tile / 3;
    const int wo0 = (tile - ho * 3) * 32;
    const int wv = t >> 6;
    const int l = t & 63;
    const int lr = l & 15;
    const int quad = l >> 4;

    const unsigned short* xTb = xT + (size_t)bb * HW * 64;

    // phase 0: stage halo region rows ho-3..ho+3, cols wo0-3..wo0+34
    static const bf16x8 zero8 = {0, 0, 0, 0, 0, 0, 0, 0};
    for (int i = t; i < RR * RC * 8; i += 256) {
        int q = i & 7;
        int rcx = i >> 3;
        int col = rcx % RC, r = rcx / RC;
        int h = ho - 3 + r, w = wo0 - 3 + col;
        bf16x8 val = zero8;
        if ((unsigned)h < (unsigned)Hh && (unsigned)w < (unsigned)Ww)
            val = *(const bf16x8*)(xTb + ((size_t)(h * Ww + w)) * 64 + q * 8);
        *(bf16x8*)&R.reg[(r * RC + col) * RS + q * 8] = val;
    }
    __syncthreads();

    // phase 1: conv 64->27 via MFMA (A from region rows 2..4, B from global)
    {
        f32x4 acc_o = {0.f, 0.f, 0.f, 0.f};
        const int mt1 = wv & 1;
        const int nt1 = wv >> 1;
#pragma unroll
        for (int k9 = 0; k9 < 9; ++k9) {
            const int di = k9 / 3, dj = k9 % 3;
            const short* ar =
                &R.reg[((di + 2) * RC + mt1 * 16 + lr + dj + 2) * RS + quad * 8];
#pragma unroll
            for (int s = 0; s < 2; ++s) {
                bf16x8 a = *(const bf16x8*)(ar + s * 32);
                bf16x8 b = *(const bf16x8*)(w27F + (((k9 * 2 + s) * 2 + nt1) << 9) + l * 8);
                acc_o = __builtin_amdgcn_mfma_f32_16x16x32_bf16(a, b, acc_o, 0, 0, 0);
            }
        }
        int ch = nt1 * 16 + lr;
        if (ch < 27) {
#pragma unroll
            for (int r = 0; r < 4; ++r)
                offm_s[ch * 33 + mt1 * 16 + quad * 4 + r] = acc_o[r];
        }
    }
    __syncthreads();

    // phase 2a: bias + 2*sigmoid
    for (int i = t; i < 27 * PT; i += 256) {
        int ch = i >> 5, pos = i & 31;
        float v = offm_s[ch * 33 + pos];
        if (ch < 18) v += ob[ch];
        else         v = 2.f / (1.f + expf(-(v + mb[ch - 18])));
        offm_s[ch * 33 + pos] = v;
    }
    __syncthreads();
    // phase 2b: bilinear params; indices region-relative (tagged global if not)
    for (int i = t; i < 9 * PT; i += 256) {
        int kk = i >> 5, pos = i & 31;
        float dy = offm_s[(2 * kk) * 33 + pos];
        float dx = offm_s[(2 * kk + 1) * 33 + pos];
        float mm = offm_s[(18 + kk) * 33 + pos];
        float py = (float)(ho - 1 + kk / 3) + dy;
        float px = (float)(wo0 + pos - 1 + kk % 3) + dx;
        float fy = floorf(py), fx = floorf(px);
        float ly = py - fy, lx = px - fx;
        int y0 = (int)fy, x0 = (int)fx;
        int y1 = y0 + 1, x1 = x0 + 1;
        float v00 = ((unsigned)y0 < (unsigned)Hh && (unsigned)x0 < (unsigned)Ww) ? 1.f : 0.f;
        float v01 = ((unsigned)y0 < (unsigned)Hh && (unsigned)x1 < (unsigned)Ww) ? 1.f : 0.f;
        float v10 = ((unsigned)y1 < (unsigned)Hh && (unsigned)x0 < (unsigned)Ww) ? 1.f : 0.f;
        float v11 = ((unsigned)y1 < (unsigned)Hh && (unsigned)x1 < (unsigned)Ww) ? 1.f : 0.f;
        s_pw[kk][0][pos] = (1.f - ly) * (1.f - lx) * mm * v00;
        s_pw[kk][1][pos] = (1.f - ly) * lx * mm * v01;
        s_pw[kk][2][pos] = ly * (1.f - lx) * mm * v10;
        s_pw[kk][3][pos] = ly * lx * mm * v11;

        auto mkidx = [&](float valid, int y, int xx) -> int {
            if (valid == 0.f) return 0;                    // weight 0: safe read
            int ry = y - (ho - 3), rx = xx - (wo0 - 3);
            if ((unsigned)ry < (unsigned)RR && (unsigned)rx < (unsigned)RC)
                return (ry * RC + rx) * RS;                // LDS element offset
            return (int)(0x80000000u | (unsigned)((y * Ww + xx) * 64));  // global
        };
        s_pi[kk][0][pos] = mkidx(v00, y0, x0);
        s_pi[kk][1][pos] = mkidx(v01, y0, x1);
        s_pi[kk][2][pos] = mkidx(v10, y1, x0);
        s_pi[kk][3][pos] = mkidx(v11, y1, x1);
    }
    __syncthreads();

    // phase 3: tap-split LDS sampling + GEMM over all 128 ocs
    const int nt = wv & 1;                   // pos half
    const int tg = wv >> 1;                  // tap group
    const int pos_l = nt * 16 + lr;
    const int cq = quad * 8;

    f32x4 acc[8];
#pragma unroll
    for (int m = 0; m < 8; ++m) acc[m] = (f32x4){0.f, 0.f, 0.f, 0.f};

    const unsigned short* wb = wTmF + l * 8;

    if (tg == 0)
        sample_gemm<0, 5>(R.reg, xTb, wb, s_pw, s_pi, pos_l, cq, acc);
    else
        sample_gemm<5, 9>(R.reg, xTb, wb, s_pw, s_pi, pos_l, cq, acc);

    __syncthreads();                          // all region/pw/pi reads done
    if (tg == 1) {
#pragma unroll
        for (int m = 0; m < 8; ++m)
            *(f32x4*)&R.mg[m * 520 + (nt * 64 + l) * 4] = acc[m];
    }
    __syncthreads();
    if (tg == 0) {
        float* outp = out + (size_t)bb * Oo * HW + tile * PT + nt * 16 + lr;
#pragma unroll
        for (int m = 0; m < 8; ++m) {
            f32x4 o = acc[m] + *(const f32x4*)&R.mg[m * 520 + (nt * 64 + l) * 4];
#pragma unroll
            for (int r = 0; r < 4; ++r) {
                int oc = m * 16 + quad * 4 + r;
                outp[(size_t)oc * HW] = o[r];
            }
        }
    }
}

extern "C" void kernel_launch(void* const* d_in, const int* in_sizes, int n_in,
                              void* d_out, int out_size, void* d_ws, size_t ws_size,
                              hipStream_t stream) {
    const float* x  = (const float*)d_in[0];
    const float* ow = (const float*)d_in[1];
    const float* ob = (const float*)d_in[2];
    const float* mw = (const float*)d_in[3];
    const float* mb = (const float*)d_in[4];
    const float* dw = (const float*)d_in[5];
    float* out = (float*)d_out;

    unsigned short* wTmF = (unsigned short*)d_ws;          // 73728 shorts
    unsigned short* w27F = wTmF + 9 * 8 * 2 * 512;         // 18432 shorts
    unsigned short* xT   = w27F + 9 * 2 * 2 * 512;         // 2359296 shorts

    hipLaunchKernelGGL(k_pre, dim3(504), dim3(256), 0, stream,
                       dw, ow, mw, x, wTmF, w27F, xT);
    hipLaunchKernelGGL(k_fused, dim3(Bc * NPB), dim3(256), 0, stream,
                       xT, ob, mb, w27F, wTmF, out);
}